// Round 4
// baseline (395.301 us; speedup 1.0000x reference)
//
#include <hip/hip_runtime.h>

#define N_RAYS    131072
#define N_SAMPLES 128
#define FAR_DELTA 1e10f

#define NBLOCKS   1024      // 4 waves each; 4096 waves x 32 rays = 131072
#define ITERS     8         // per wave: 8 iters x 4 rays

// DPP controls (gfx9): row ops act within 16-lane rows (== one ray segment).
//   row_shr:n -> lane i reads lane i-n (prefix-scan dir); row_shl:n -> lane i+n
#define ROW_SHL(n) (0x100 + (n))
#define ROW_SHR(n) (0x110 + (n))
#define QPERM(a,b,c,d) ((a) | ((b) << 2) | ((c) << 4) | ((d) << 6))

template <int CTRL>
__device__ __forceinline__ float dpp_f(float v, float ident) {
    return __int_as_float(__builtin_amdgcn_update_dpp(
        __float_as_int(ident), __float_as_int(v), CTRL, 0xF, 0xF, false));
}

// Wave-private LDS layout (13312 B per wave):
//   feature: 64 lanes x 112 B  (96 B data + 16 B pad -> 28-word stride, conflict-free b128)
//   density: 64 lanes x  48 B  (32 B data + 16 B pad -> 12-word stride, conflict-free)
//   depth  : 64 lanes x  48 B
#define WAVE_LDS  13312
#define FEAT_STR  112
#define DD_STR    48
#define DEN_OFF   7168
#define DEP_OFF   10240

__global__ __launch_bounds__(256, 3) void VolumeRenderer_57612691308835_kernel(
    const float* __restrict__ density,      // [N, S]
    const float* __restrict__ feature,      // [N, S, 3]
    const float* __restrict__ depth,        // [N, S]
    float* __restrict__ out_feat,           // [N, 3]
    float* __restrict__ out_depth)          // [N]
{
    __shared__ char lds[4 * WAVE_LDS];

    const int tid  = threadIdx.x;
    const int wave = tid >> 6;
    const int lane = tid & 63;
    const int p    = lane & 15;             // position within 16-lane row
    const int g    = lane >> 4;             // which ray of this wave's 4

    char* wlds = lds + wave * WAVE_LDS;

    // Per-lane constant LDS read addresses (lane = 16*g + p).
    char* fR  = wlds + lane * FEAT_STR;               // 6 x float4 at +16*c
    char* dnR = wlds + DEN_OFF + lane * DD_STR;       // 2 x float4
    char* dpR = wlds + DEP_OFF + lane * DD_STR;

    // Per-lane constant LDS write addresses: staging lane holds global float4
    // chunk q = c*64 + lane of the wave's 4-ray span.
    int wf[6], wdn[2], wdp[2];
    #pragma unroll
    for (int c = 0; c < 6; ++c) {
        const int q  = c * 64 + lane;       // feature: 96 float4 per ray
        const int gg = q / 96;
        const int r  = q - gg * 96;
        const int pp = r / 6;
        const int cc = r - pp * 6;
        wf[c] = gg * (16 * FEAT_STR) + pp * FEAT_STR + cc * 16;
    }
    #pragma unroll
    for (int c = 0; c < 2; ++c) {
        const int q  = c * 64 + lane;       // den/dep: 32 float4 per ray
        const int gg = q >> 5;
        const int r  = q & 31;
        const int pp = r >> 1;
        const int cc = r & 1;
        wdn[c] = DEN_OFF + gg * (16 * DD_STR) + pp * DD_STR + cc * 16;
        wdp[c] = DEP_OFF + gg * (16 * DD_STR) + pp * DD_STR + cc * 16;
    }

    // Global bases: this wave's first ray; lane-contiguous float4 loads.
    const long wray = ((long)blockIdx.x * 4 + wave) * 32;
    const float4* fG  = (const float4*)feature + wray * 96 + lane;
    const float4* dnG = (const float4*)density + wray * 32 + lane;
    const float4* dpG = (const float4*)depth   + wray * 32 + lane;

    struct Buf { float4 f[6]; float4 dn[2]; float4 dp[2]; };
    Buf A, B;

    auto LOAD = [&](Buf& b, int it) {
        const int fo = it * 384, do_ = it * 128;
        #pragma unroll
        for (int c = 0; c < 6; ++c) b.f[c] = fG[fo + c * 64];
        #pragma unroll
        for (int c = 0; c < 2; ++c) {
            b.dn[c] = dnG[do_ + c * 64];
            b.dp[c] = dpG[do_ + c * 64];
        }
    };

    auto PROC = [&](const Buf& b, int it) {
        // Stage to wave-private LDS (no barrier needed: same-wave DS ops are
        // FIFO-ordered; reads below are issued after these writes).
        #pragma unroll
        for (int c = 0; c < 6; ++c) *(float4*)(wlds + wf[c]) = b.f[c];
        #pragma unroll
        for (int c = 0; c < 2; ++c) {
            *(float4*)(wlds + wdn[c]) = b.dn[c];
            *(float4*)(wlds + wdp[c]) = b.dp[c];
        }

        // Per-lane sample-blocked reads (conflict-free strides).
        const float4 dn0 = *(const float4*)(dnR);
        const float4 dn1 = *(const float4*)(dnR + 16);
        const float4 dp0 = *(const float4*)(dpR);
        const float4 dp1 = *(const float4*)(dpR + 16);
        const float4 f0 = *(const float4*)(fR);
        const float4 f1 = *(const float4*)(fR + 16);
        const float4 f2 = *(const float4*)(fR + 32);
        const float4 f3 = *(const float4*)(fR + 48);
        const float4 f4 = *(const float4*)(fR + 64);
        const float4 f5 = *(const float4*)(fR + 80);

        // deltas: depth[s+1]-depth[s]; lane needs NEXT lane's first depth.
        const float dnext = dpp_f<ROW_SHL(1)>(dp0.x, 0.0f);
        const float d7 = (p == 15) ? FAR_DELTA : (dnext - dp1.w);

        const float a0 = __expf(-dn0.x * (dp0.y - dp0.x));
        const float a1 = __expf(-dn0.y * (dp0.z - dp0.y));
        const float a2 = __expf(-dn0.z * (dp0.w - dp0.z));
        const float a3 = __expf(-dn0.w * (dp1.x - dp0.w));
        const float a4 = __expf(-dn1.x * (dp1.y - dp1.x));
        const float a5 = __expf(-dn1.y * (dp1.z - dp1.y));
        const float a6 = __expf(-dn1.z * (dp1.w - dp1.z));
        const float a7 = __expf(-dn1.w * d7);

        // Per-lane product, then segmented inclusive scan over the 16-lane row.
        float s = ((a0 * a1) * (a2 * a3)) * ((a4 * a5) * (a6 * a7));
        s *= dpp_f<ROW_SHR(1)>(s, 1.0f);
        s *= dpp_f<ROW_SHR(2)>(s, 1.0f);
        s *= dpp_f<ROW_SHR(4)>(s, 1.0f);
        s *= dpp_f<ROW_SHR(8)>(s, 1.0f);
        float T = dpp_f<ROW_SHR(1)>(s, 1.0f);   // exclusive prefix; lane 0 -> 1

        T *= a0; const float w0 = T * (1.0f - a0);
        T *= a1; const float w1 = T * (1.0f - a1);
        T *= a2; const float w2 = T * (1.0f - a2);
        T *= a3; const float w3 = T * (1.0f - a3);
        T *= a4; const float w4 = T * (1.0f - a4);
        T *= a5; const float w5 = T * (1.0f - a5);
        T *= a6; const float w6 = T * (1.0f - a6);
        T *= a7; const float w7 = T * (1.0f - a7);

        float fx = w0*f0.x + w1*f0.w + w2*f1.z + w3*f2.y + w4*f3.x + w5*f3.w + w6*f4.z + w7*f5.y;
        float fy = w0*f0.y + w1*f1.x + w2*f1.w + w3*f2.z + w4*f3.y + w5*f4.x + w6*f4.w + w7*f5.z;
        float fz = w0*f0.z + w1*f1.y + w2*f2.x + w3*f2.w + w4*f3.z + w5*f4.y + w6*f5.x + w7*f5.w;
        float dd = w0*dp0.x + w1*dp0.y + w2*dp0.z + w3*dp0.w + w4*dp1.x + w5*dp1.y + w6*dp1.z + w7*dp1.w;

        // Reduce toward low lanes, then 4x4 quad transpose-reduce.
        fx += dpp_f<ROW_SHL(8)>(fx, 0.0f);
        fy += dpp_f<ROW_SHL(8)>(fy, 0.0f);
        fz += dpp_f<ROW_SHL(8)>(fz, 0.0f);
        dd += dpp_f<ROW_SHL(8)>(dd, 0.0f);
        fx += dpp_f<ROW_SHL(4)>(fx, 0.0f);
        fy += dpp_f<ROW_SHL(4)>(fy, 0.0f);
        fz += dpp_f<ROW_SHL(4)>(fz, 0.0f);
        dd += dpp_f<ROW_SHL(4)>(dd, 0.0f);

        const bool o1 = (p & 1);
        const float sA = o1 ? fx : fy;
        const float rA = dpp_f<QPERM(1, 0, 3, 2)>(sA, 0.0f);
        float fy2 = fy, fx2 = fx;
        if (o1) fy2 += rA; else fx2 += rA;
        const float sB = o1 ? fz : dd;
        const float rB = dpp_f<QPERM(1, 0, 3, 2)>(sB, 0.0f);
        float dd2 = dd, fz2 = fz;
        if (o1) dd2 += rB; else fz2 += rB;
        const float own = (p & 2) ? (o1 ? dd2 : fz2) : (o1 ? fy2 : fx2);
        const float sC  = (p & 2) ? (o1 ? fy2 : fx2) : (o1 ? dd2 : fz2);
        const float rC  = dpp_f<QPERM(2, 3, 0, 1)>(sC, 0.0f);
        const float res = own + rC;

        const int ray = (int)wray + it * 4 + g;
        if (p < 3)       out_feat[ray * 3 + p] = res;
        else if (p == 3) out_depth[ray] = res;
    };

    // Software pipeline: next iteration's global loads in flight while the
    // current iteration stages/computes. All buffer refs compile-time (no
    // runtime-indexed arrays -> no scratch).
    LOAD(A, 0);
    #pragma unroll
    for (int it = 0; it < ITERS; it += 2) {
        if (it + 1 < ITERS) LOAD(B, it + 1);
        PROC(A, it);
        if (it + 2 < ITERS) LOAD(A, it + 2);
        PROC(B, it + 1);
    }
}

extern "C" void kernel_launch(void* const* d_in, const int* in_sizes, int n_in,
                              void* d_out, int out_size, void* d_ws, size_t ws_size,
                              hipStream_t stream) {
    const float* density = (const float*)d_in[0];   // [N, S]
    const float* feature = (const float*)d_in[1];   // [N, S, 3]
    const float* depth   = (const float*)d_in[2];   // [N, S]

    float* out_feat  = (float*)d_out;                       // [N, 3] flat first
    float* out_depth = (float*)d_out + (long)N_RAYS * 3;    // [N] after

    VolumeRenderer_57612691308835_kernel<<<NBLOCKS, 256, 0, stream>>>(
        density, feature, depth, out_feat, out_depth);
}

// Round 5
// 354.383 us; speedup vs baseline: 1.1155x; 1.1155x over previous
//
#include <hip/hip_runtime.h>

#define N_RAYS    131072
#define N_SAMPLES 128
#define FAR_DELTA 1e10f

#define NBLOCKS   1024      // 4 waves each; 4096 waves x 32 rays = 131072

// DPP controls (gfx9): row ops act within 16-lane rows (== one ray segment).
//   row_shr:n -> lane i reads lane i-n (prefix-scan dir); row_shl:n -> lane i+n
#define ROW_SHL(n) (0x100 + (n))
#define ROW_SHR(n) (0x110 + (n))
#define QPERM(a,b,c,d) ((a) | ((b) << 2) | ((c) << 4) | ((d) << 6))

template <int CTRL>
__device__ __forceinline__ float dpp_f(float v, float ident) {
    return __int_as_float(__builtin_amdgcn_update_dpp(
        __float_as_int(ident), __float_as_int(v), CTRL, 0xF, 0xF, false));
}

// Wave-private LDS layout (13312 B per wave):
//   feature: 64 lanes x 112 B (96 B data + 16 B pad -> conflict-free b128)
//   density: 64 lanes x  48 B (32 B data + 16 B pad)
//   depth  : 64 lanes x  48 B
#define WAVE_LDS  13312
#define FEAT_STR  112
#define DD_STR    48
#define DEN_OFF   7168
#define DEP_OFF   10240

// LDS write offsets: staging lane holds global float4 chunk q = c*64 + lane
// of the wave's current 4-ray span. Pure scalar math, returned by value.
__device__ __forceinline__ int feat_woff(int lane, int c) {
    const int q  = c * 64 + lane;           // feature: 96 float4 per ray
    const int gg = q / 96;
    const int r  = q - gg * 96;
    const int pp = r / 6;
    const int cc = r - pp * 6;
    return gg * (16 * FEAT_STR) + pp * FEAT_STR + cc * 16;
}
__device__ __forceinline__ int dd_woff(int lane, int c, int regionOff) {
    const int q  = c * 64 + lane;           // den/dep: 32 float4 per ray
    const int gg = q >> 5;
    const int r  = q & 31;
    const int pp = r >> 1;
    const int cc = r & 1;
    return regionOff + gg * (16 * DD_STR) + pp * DD_STR + cc * 16;
}

// ---- pipeline stages as macros on NAMED float4 scalars (nothing address-
// taken, no structs, no runtime-indexed arrays -> no scratch spill) ----

#define LOADM(F0,F1,F2,F3,F4,F5,DN0,DN1,DP0,DP1,IT) do {                     \
    const int fo_ = (IT) * 384, dd_ = (IT) * 128;                            \
    F0 = fG[fo_];       F1 = fG[fo_ + 64];   F2 = fG[fo_ + 128];             \
    F3 = fG[fo_ + 192]; F4 = fG[fo_ + 256];  F5 = fG[fo_ + 320];             \
    DN0 = dnG[dd_];     DN1 = dnG[dd_ + 64];                                 \
    DP0 = dpG[dd_];     DP1 = dpG[dd_ + 64];                                 \
} while (0)

#define PROCM(F0,F1,F2,F3,F4,F5,DN0,DN1,DP0,DP1,IT) do {                     \
    /* stage to wave-private LDS (same-wave DS ops are in-order: no barrier)*/\
    *(float4*)(wlds + wf0) = F0;  *(float4*)(wlds + wf1) = F1;               \
    *(float4*)(wlds + wf2) = F2;  *(float4*)(wlds + wf3) = F3;               \
    *(float4*)(wlds + wf4) = F4;  *(float4*)(wlds + wf5) = F5;               \
    *(float4*)(wlds + wdn0) = DN0; *(float4*)(wlds + wdn1) = DN1;            \
    *(float4*)(wlds + wdp0) = DP0; *(float4*)(wlds + wdp1) = DP1;            \
    /* per-lane sample-blocked reads (conflict-free strides) */              \
    const float4 dn0 = *(const float4*)(dnR);                                \
    const float4 dn1 = *(const float4*)(dnR + 16);                           \
    const float4 dp0 = *(const float4*)(dpR);                                \
    const float4 dp1 = *(const float4*)(dpR + 16);                           \
    const float4 f0 = *(const float4*)(fR);                                  \
    const float4 f1 = *(const float4*)(fR + 16);                             \
    const float4 f2 = *(const float4*)(fR + 32);                             \
    const float4 f3 = *(const float4*)(fR + 48);                             \
    const float4 f4 = *(const float4*)(fR + 64);                             \
    const float4 f5 = *(const float4*)(fR + 80);                             \
    /* deltas: depth[s+1]-depth[s]; lane needs NEXT lane's first depth */    \
    const float dnext = dpp_f<ROW_SHL(1)>(dp0.x, 0.0f);                      \
    const float d7 = (p == 15) ? FAR_DELTA : (dnext - dp1.w);                \
    const float a0 = __expf(-dn0.x * (dp0.y - dp0.x));                       \
    const float a1 = __expf(-dn0.y * (dp0.z - dp0.y));                       \
    const float a2 = __expf(-dn0.z * (dp0.w - dp0.z));                       \
    const float a3 = __expf(-dn0.w * (dp1.x - dp0.w));                       \
    const float a4 = __expf(-dn1.x * (dp1.y - dp1.x));                       \
    const float a5 = __expf(-dn1.y * (dp1.z - dp1.y));                       \
    const float a6 = __expf(-dn1.z * (dp1.w - dp1.z));                       \
    const float a7 = __expf(-dn1.w * d7);                                    \
    /* per-lane product, then segmented inclusive scan over the 16-lane row*/\
    float s = ((a0 * a1) * (a2 * a3)) * ((a4 * a5) * (a6 * a7));             \
    s *= dpp_f<ROW_SHR(1)>(s, 1.0f);                                         \
    s *= dpp_f<ROW_SHR(2)>(s, 1.0f);                                         \
    s *= dpp_f<ROW_SHR(4)>(s, 1.0f);                                         \
    s *= dpp_f<ROW_SHR(8)>(s, 1.0f);                                         \
    float T = dpp_f<ROW_SHR(1)>(s, 1.0f);   /* exclusive; lane 0 -> 1 */     \
    T *= a0; const float w0 = T * (1.0f - a0);                               \
    T *= a1; const float w1 = T * (1.0f - a1);                               \
    T *= a2; const float w2 = T * (1.0f - a2);                               \
    T *= a3; const float w3 = T * (1.0f - a3);                               \
    T *= a4; const float w4 = T * (1.0f - a4);                               \
    T *= a5; const float w5 = T * (1.0f - a5);                               \
    T *= a6; const float w6 = T * (1.0f - a6);                               \
    T *= a7; const float w7 = T * (1.0f - a7);                               \
    float fx = w0*f0.x + w1*f0.w + w2*f1.z + w3*f2.y                         \
             + w4*f3.x + w5*f3.w + w6*f4.z + w7*f5.y;                        \
    float fy = w0*f0.y + w1*f1.x + w2*f1.w + w3*f2.z                         \
             + w4*f3.y + w5*f4.x + w6*f4.w + w7*f5.z;                        \
    float fz = w0*f0.z + w1*f1.y + w2*f2.x + w3*f2.w                         \
             + w4*f3.z + w5*f4.y + w6*f5.x + w7*f5.w;                        \
    float dd = w0*dp0.x + w1*dp0.y + w2*dp0.z + w3*dp0.w                     \
             + w4*dp1.x + w5*dp1.y + w6*dp1.z + w7*dp1.w;                    \
    /* reduce toward low lanes, then 4x4 quad transpose-reduce */            \
    fx += dpp_f<ROW_SHL(8)>(fx, 0.0f);                                       \
    fy += dpp_f<ROW_SHL(8)>(fy, 0.0f);                                       \
    fz += dpp_f<ROW_SHL(8)>(fz, 0.0f);                                       \
    dd += dpp_f<ROW_SHL(8)>(dd, 0.0f);                                       \
    fx += dpp_f<ROW_SHL(4)>(fx, 0.0f);                                       \
    fy += dpp_f<ROW_SHL(4)>(fy, 0.0f);                                       \
    fz += dpp_f<ROW_SHL(4)>(fz, 0.0f);                                       \
    dd += dpp_f<ROW_SHL(4)>(dd, 0.0f);                                       \
    const bool o1 = (p & 1);                                                 \
    const float sA = o1 ? fx : fy;                                           \
    const float rA = dpp_f<QPERM(1, 0, 3, 2)>(sA, 0.0f);                     \
    float fy2 = fy, fx2 = fx;                                                \
    if (o1) fy2 += rA; else fx2 += rA;                                       \
    const float sB = o1 ? fz : dd;                                           \
    const float rB = dpp_f<QPERM(1, 0, 3, 2)>(sB, 0.0f);                     \
    float dd2 = dd, fz2 = fz;                                                \
    if (o1) dd2 += rB; else fz2 += rB;                                       \
    const float own = (p & 2) ? (o1 ? dd2 : fz2) : (o1 ? fy2 : fx2);         \
    const float sC  = (p & 2) ? (o1 ? fy2 : fx2) : (o1 ? dd2 : fz2);         \
    const float rC  = dpp_f<QPERM(2, 3, 0, 1)>(sC, 0.0f);                    \
    const float res = own + rC;                                              \
    const int ray = (int)wray + (IT) * 4 + g;                                \
    if (p < 3)       out_feat[ray * 3 + p] = res;                            \
    else if (p == 3) out_depth[ray] = res;                                   \
} while (0)

#define LOAD_A(IT) LOADM(fA0,fA1,fA2,fA3,fA4,fA5,dnA0,dnA1,dpA0,dpA1,IT)
#define LOAD_B(IT) LOADM(fB0,fB1,fB2,fB3,fB4,fB5,dnB0,dnB1,dpB0,dpB1,IT)
#define PROC_A(IT) PROCM(fA0,fA1,fA2,fA3,fA4,fA5,dnA0,dnA1,dpA0,dpA1,IT)
#define PROC_B(IT) PROCM(fB0,fB1,fB2,fB3,fB4,fB5,dnB0,dnB1,dpB0,dpB1,IT)

__global__ __launch_bounds__(256, 3) void VolumeRenderer_57612691308835_kernel(
    const float* __restrict__ density,      // [N, S]
    const float* __restrict__ feature,      // [N, S, 3]
    const float* __restrict__ depth,        // [N, S]
    float* __restrict__ out_feat,           // [N, 3]
    float* __restrict__ out_depth)          // [N]
{
    __shared__ char lds[4 * WAVE_LDS];

    const int tid  = threadIdx.x;
    const int wave = tid >> 6;
    const int lane = tid & 63;
    const int p    = lane & 15;             // position within 16-lane row
    const int g    = lane >> 4;             // which ray of this wave's 4

    char* wlds = lds + wave * WAVE_LDS;

    // Per-lane constant LDS read addresses (lane = 16*g + p).
    char* fR  = wlds + lane * FEAT_STR;               // 6 x float4 at +16*c
    char* dnR = wlds + DEN_OFF + lane * DD_STR;       // 2 x float4
    char* dpR = wlds + DEP_OFF + lane * DD_STR;

    // Per-lane constant LDS write offsets (named scalars — SROA-safe).
    const int wf0 = feat_woff(lane, 0), wf1 = feat_woff(lane, 1);
    const int wf2 = feat_woff(lane, 2), wf3 = feat_woff(lane, 3);
    const int wf4 = feat_woff(lane, 4), wf5 = feat_woff(lane, 5);
    const int wdn0 = dd_woff(lane, 0, DEN_OFF), wdn1 = dd_woff(lane, 1, DEN_OFF);
    const int wdp0 = dd_woff(lane, 0, DEP_OFF), wdp1 = dd_woff(lane, 1, DEP_OFF);

    // Global bases: this wave's first ray; lane-contiguous float4 loads.
    const long wray = ((long)blockIdx.x * 4 + wave) * 32;
    const float4* fG  = (const float4*)feature + wray * 96 + lane;
    const float4* dnG = (const float4*)density + wray * 32 + lane;
    const float4* dpG = (const float4*)depth   + wray * 32 + lane;

    // Double-buffer in NAMED registers.
    float4 fA0, fA1, fA2, fA3, fA4, fA5, dnA0, dnA1, dpA0, dpA1;
    float4 fB0, fB1, fB2, fB3, fB4, fB5, dnB0, dnB1, dpB0, dpB1;

    // Software pipeline: next iteration's global loads in flight while the
    // current iteration stages/computes. 8 iterations, fully unrolled.
    LOAD_A(0);
    LOAD_B(1);  PROC_A(0);  LOAD_A(2);  PROC_B(1);
    LOAD_B(3);  PROC_A(2);  LOAD_A(4);  PROC_B(3);
    LOAD_B(5);  PROC_A(4);  LOAD_A(6);  PROC_B(5);
    LOAD_B(7);  PROC_A(6);              PROC_B(7);
}

extern "C" void kernel_launch(void* const* d_in, const int* in_sizes, int n_in,
                              void* d_out, int out_size, void* d_ws, size_t ws_size,
                              hipStream_t stream) {
    const float* density = (const float*)d_in[0];   // [N, S]
    const float* feature = (const float*)d_in[1];   // [N, S, 3]
    const float* depth   = (const float*)d_in[2];   // [N, S]

    float* out_feat  = (float*)d_out;                       // [N, 3] flat first
    float* out_depth = (float*)d_out + (long)N_RAYS * 3;    // [N] after

    VolumeRenderer_57612691308835_kernel<<<NBLOCKS, 256, 0, stream>>>(
        density, feature, depth, out_feat, out_depth);
}